// Round 1
// baseline (1009.772 us; speedup 1.0000x reference)
//
#include <hip/hip_runtime.h>
#include <math.h>

#define EMBED  1024
#define NHEADS 16
#define DH     64
#define BATCH  2
#define SEQ    2048
#define M_TOT  (BATCH*SEQ)   // 4096 rows

// ---------------------------------------------------------------------------
// Kernel 1: qkv = x @ W_kqv + b_kqv, scattered into Q/K/V [B,H,T,Dh] (fp32).
// Q is pre-scaled by 1/sqrt(Dh) = 0.125.
// Tiling: BM=BN=64, BK=16, 256 threads, 4x4 micro-tile per thread.
// ---------------------------------------------------------------------------
__global__ __launch_bounds__(256)
void qkv_gemm_kernel(const float* __restrict__ X, const float* __restrict__ W,
                     const float* __restrict__ bias,
                     float* __restrict__ Q, float* __restrict__ Kmat,
                     float* __restrict__ V)
{
    constexpr int K = EMBED, N = 3 * EMBED;
    __shared__ __align__(16) float As[16][68];
    __shared__ __align__(16) float Bs[16][68];

    const int tid = threadIdx.x;
    const int tx = tid & 15, ty = tid >> 4;
    const int m0 = blockIdx.y * 64, n0 = blockIdx.x * 64;

    const int la_k = tid & 15, la_m = tid >> 4;   // A tile loader coords
    const int lb_n = tid & 63, lb_k = tid >> 6;   // B tile loader coords

    float c[4][4] = {{0.f, 0.f, 0.f, 0.f}, {0.f, 0.f, 0.f, 0.f},
                     {0.f, 0.f, 0.f, 0.f}, {0.f, 0.f, 0.f, 0.f}};

    for (int k0 = 0; k0 < K; k0 += 16) {
#pragma unroll
        for (int i = 0; i < 4; ++i)
            As[la_k][la_m + i * 16] =
                X[(size_t)(m0 + la_m + i * 16) * K + (k0 + la_k)];
#pragma unroll
        for (int i = 0; i < 4; ++i)
            Bs[lb_k + i * 4][lb_n] =
                W[(size_t)(k0 + lb_k + i * 4) * N + (n0 + lb_n)];
        __syncthreads();

#pragma unroll
        for (int kk = 0; kk < 16; ++kk) {
            float4 a4 = *(const float4*)&As[kk][ty * 4];
            float4 b4 = *(const float4*)&Bs[kk][tx * 4];
            float av[4] = {a4.x, a4.y, a4.z, a4.w};
            float bv[4] = {b4.x, b4.y, b4.z, b4.w};
#pragma unroll
            for (int i = 0; i < 4; ++i)
#pragma unroll
                for (int j = 0; j < 4; ++j)
                    c[i][j] = fmaf(av[i], bv[j], c[i][j]);
        }
        __syncthreads();
    }

    // Epilogue: add bias, scatter to Q/K/V in [B*H, T, DH] layout.
#pragma unroll
    for (int i = 0; i < 4; ++i) {
        const int m = m0 + ty * 4 + i;
        const int bb = m >> 11;            // m / SEQ
        const int t  = m & (SEQ - 1);
#pragma unroll
        for (int j = 0; j < 4; ++j) {
            const int n = n0 + tx * 4 + j;
            float val = c[i][j] + bias[n];
            const int sec = n >> 10;       // 0=q, 1=k, 2=v
            const int cc  = n & (EMBED - 1);
            const int h   = cc >> 6;
            const int d   = cc & 63;
            const size_t idx = (((size_t)(bb * NHEADS + h)) * SEQ + t) * DH + d;
            if (sec == 0)      Q[idx]    = val * 0.125f;
            else if (sec == 1) Kmat[idx] = val;
            else               V[idx]    = val;
        }
    }
}

// ---------------------------------------------------------------------------
// Kernel 2: causal flash attention, fp32.
// One block per (b*h, q-tile of 64). 256 threads = 16x16 grid, 4x4 micro.
// Thread (tx,ty): q rows = ty*4+i, k cols = tx + 16*j (strided for LDS banks).
// QPs buffer is Q-tile during score phase, P-tile during PV phase (LDS cap).
// ---------------------------------------------------------------------------
__global__ __launch_bounds__(256)
void attn_kernel(const float* __restrict__ Q, const float* __restrict__ K,
                 const float* __restrict__ V, float* __restrict__ Y)
{
    __shared__ __align__(16) float QPs[64][68];
    __shared__ __align__(16) float Ks[64][68];
    __shared__ __align__(16) float Vs[64][64];

    const int tid = threadIdx.x;
    const int tx = tid & 15, ty = tid >> 4;
    const int qt = blockIdx.x;
    const int bh = blockIdx.y;
    const int b = bh >> 4, h = bh & 15;

    const float* Qb = Q + (size_t)bh * SEQ * DH;
    const float* Kb = K + (size_t)bh * SEQ * DH;
    const float* Vb = V + (size_t)bh * SEQ * DH;

    const int lr = tid >> 4;           // loader row 0..15
    const int lc = (tid & 15) * 4;     // loader col (float4) 0..60

    float m_i[4], l_i[4], acc[4][4];
#pragma unroll
    for (int i = 0; i < 4; ++i) {
        m_i[i] = -INFINITY;
        l_i[i] = 0.f;
#pragma unroll
        for (int j = 0; j < 4; ++j) acc[i][j] = 0.f;
    }

    for (int kt = 0; kt <= qt; ++kt) {
        __syncthreads();   // previous iteration done reading QPs(P)/Vs
        // Load Q (re-load: QPs was overwritten by P), K, V tiles.
#pragma unroll
        for (int i = 0; i < 4; ++i) {
            const int r = lr + i * 16;
            *(float4*)&QPs[r][lc] =
                *(const float4*)&Qb[(size_t)(qt * 64 + r) * DH + lc];
            *(float4*)&Ks[r][lc] =
                *(const float4*)&Kb[(size_t)(kt * 64 + r) * DH + lc];
            *(float4*)&Vs[r][lc] =
                *(const float4*)&Vb[(size_t)(kt * 64 + r) * DH + lc];
        }
        __syncthreads();

        // Scores: s[i][j] = q_row(ty*4+i) . k_col(tx+16j)   (Q pre-scaled)
        float s[4][4] = {{0.f, 0.f, 0.f, 0.f}, {0.f, 0.f, 0.f, 0.f},
                         {0.f, 0.f, 0.f, 0.f}, {0.f, 0.f, 0.f, 0.f}};
#pragma unroll
        for (int d0 = 0; d0 < DH; d0 += 4) {
            float qv[4][4], kv[4][4];
#pragma unroll
            for (int i = 0; i < 4; ++i) {
                float4 t4 = *(const float4*)&QPs[ty * 4 + i][d0];
                qv[i][0] = t4.x; qv[i][1] = t4.y; qv[i][2] = t4.z; qv[i][3] = t4.w;
            }
#pragma unroll
            for (int j = 0; j < 4; ++j) {
                float4 t4 = *(const float4*)&Ks[tx + 16 * j][d0];
                kv[j][0] = t4.x; kv[j][1] = t4.y; kv[j][2] = t4.z; kv[j][3] = t4.w;
            }
#pragma unroll
            for (int i = 0; i < 4; ++i)
#pragma unroll
                for (int j = 0; j < 4; ++j)
#pragma unroll
                    for (int d = 0; d < 4; ++d)
                        s[i][j] = fmaf(qv[i][d], kv[j][d], s[i][j]);
        }

        if (kt == qt) {   // causal mask within diagonal tile
#pragma unroll
            for (int i = 0; i < 4; ++i)
#pragma unroll
                for (int j = 0; j < 4; ++j)
                    if (tx + 16 * j > ty * 4 + i) s[i][j] = -INFINITY;
        }

        // Online softmax (row reduce over 16 lanes sharing ty).
        float p[4][4];
#pragma unroll
        for (int i = 0; i < 4; ++i) {
            float mx = fmaxf(fmaxf(s[i][0], s[i][1]), fmaxf(s[i][2], s[i][3]));
#pragma unroll
            for (int off = 1; off < 16; off <<= 1)
                mx = fmaxf(mx, __shfl_xor(mx, off));
            const float mn = fmaxf(m_i[i], mx);
            const float alpha = __expf(m_i[i] - mn);   // 0 when m_i = -inf
            float lsum = 0.f;
#pragma unroll
            for (int j = 0; j < 4; ++j) {
                p[i][j] = __expf(s[i][j] - mn);
                lsum += p[i][j];
            }
#pragma unroll
            for (int off = 1; off < 16; off <<= 1)
                lsum += __shfl_xor(lsum, off);
            l_i[i] = l_i[i] * alpha + lsum;
            m_i[i] = mn;
#pragma unroll
            for (int j = 0; j < 4; ++j) acc[i][j] *= alpha;
        }

        __syncthreads();   // done reading QPs as Q
        // Write P into QPs (column layout matches score layout).
#pragma unroll
        for (int i = 0; i < 4; ++i)
#pragma unroll
            for (int j = 0; j < 4; ++j)
                QPs[ty * 4 + i][tx + 16 * j] = p[i][j];
        __syncthreads();

        // PV: acc[i][j] += sum_kk P[qrow][kk] * V[kk][tx*4+j]
#pragma unroll
        for (int k0 = 0; k0 < 64; k0 += 4) {
            float pv[4][4];
#pragma unroll
            for (int i = 0; i < 4; ++i) {
                float4 t4 = *(const float4*)&QPs[ty * 4 + i][k0];
                pv[i][0] = t4.x; pv[i][1] = t4.y; pv[i][2] = t4.z; pv[i][3] = t4.w;
            }
#pragma unroll
            for (int t = 0; t < 4; ++t) {
                float4 v4 = *(const float4*)&Vs[k0 + t][tx * 4];
                float vv[4] = {v4.x, v4.y, v4.z, v4.w};
#pragma unroll
                for (int i = 0; i < 4; ++i)
#pragma unroll
                    for (int j = 0; j < 4; ++j)
                        acc[i][j] = fmaf(pv[i][t], vv[j], acc[i][j]);
            }
        }
    }

    // Normalize and write Y in [B, T, C] layout (C index = h*64 + d).
#pragma unroll
    for (int i = 0; i < 4; ++i) {
        const float inv = 1.f / l_i[i];
        const int qq = qt * 64 + ty * 4 + i;
        float4 o;
        o.x = acc[i][0] * inv; o.y = acc[i][1] * inv;
        o.z = acc[i][2] * inv; o.w = acc[i][3] * inv;
        *(float4*)&Y[((size_t)(b * SEQ + qq)) * EMBED + h * DH + tx * 4] = o;
    }
}

// ---------------------------------------------------------------------------
// Kernel 3: out = Y @ W_out + b_out  (fp32). Same tiling as kernel 1.
// ---------------------------------------------------------------------------
__global__ __launch_bounds__(256)
void out_gemm_kernel(const float* __restrict__ Yin, const float* __restrict__ W,
                     const float* __restrict__ bias, float* __restrict__ out)
{
    constexpr int K = EMBED, N = EMBED;
    __shared__ __align__(16) float As[16][68];
    __shared__ __align__(16) float Bs[16][68];

    const int tid = threadIdx.x;
    const int tx = tid & 15, ty = tid >> 4;
    const int m0 = blockIdx.y * 64, n0 = blockIdx.x * 64;

    const int la_k = tid & 15, la_m = tid >> 4;
    const int lb_n = tid & 63, lb_k = tid >> 6;

    float c[4][4] = {{0.f, 0.f, 0.f, 0.f}, {0.f, 0.f, 0.f, 0.f},
                     {0.f, 0.f, 0.f, 0.f}, {0.f, 0.f, 0.f, 0.f}};

    for (int k0 = 0; k0 < K; k0 += 16) {
#pragma unroll
        for (int i = 0; i < 4; ++i)
            As[la_k][la_m + i * 16] =
                Yin[(size_t)(m0 + la_m + i * 16) * K + (k0 + la_k)];
#pragma unroll
        for (int i = 0; i < 4; ++i)
            Bs[lb_k + i * 4][lb_n] =
                W[(size_t)(k0 + lb_k + i * 4) * N + (n0 + lb_n)];
        __syncthreads();

#pragma unroll
        for (int kk = 0; kk < 16; ++kk) {
            float4 a4 = *(const float4*)&As[kk][ty * 4];
            float4 b4 = *(const float4*)&Bs[kk][tx * 4];
            float av[4] = {a4.x, a4.y, a4.z, a4.w};
            float bv[4] = {b4.x, b4.y, b4.z, b4.w};
#pragma unroll
            for (int i = 0; i < 4; ++i)
#pragma unroll
                for (int j = 0; j < 4; ++j)
                    c[i][j] = fmaf(av[i], bv[j], c[i][j]);
        }
        __syncthreads();
    }

#pragma unroll
    for (int i = 0; i < 4; ++i) {
        const int m = m0 + ty * 4 + i;
        const int n = n0 + tx * 4;
        float4 b4 = *(const float4*)&bias[n];
        float4 o;
        o.x = c[i][0] + b4.x; o.y = c[i][1] + b4.y;
        o.z = c[i][2] + b4.z; o.w = c[i][3] + b4.w;
        *(float4*)&out[(size_t)m * N + n] = o;
    }
}

// ---------------------------------------------------------------------------
extern "C" void kernel_launch(void* const* d_in, const int* in_sizes, int n_in,
                              void* d_out, int out_size, void* d_ws, size_t ws_size,
                              hipStream_t stream)
{
    const float* x     = (const float*)d_in[0];
    const float* W_kqv = (const float*)d_in[1];
    const float* b_kqv = (const float*)d_in[2];
    const float* W_out = (const float*)d_in[3];
    const float* b_out = (const float*)d_in[4];
    float* out = (float*)d_out;

    // Workspace: Q, K, V, Y — 16 MB each (fp32), 64 MB total.
    float* Q  = (float*)d_ws;
    float* Km = Q  + (size_t)M_TOT * EMBED;
    float* V  = Km + (size_t)M_TOT * EMBED;
    float* Y  = V  + (size_t)M_TOT * EMBED;

    qkv_gemm_kernel<<<dim3(3 * EMBED / 64, M_TOT / 64), 256, 0, stream>>>(
        x, W_kqv, b_kqv, Q, Km, V);
    attn_kernel<<<dim3(SEQ / 64, BATCH * NHEADS), 256, 0, stream>>>(Q, Km, V, Y);
    out_gemm_kernel<<<dim3(EMBED / 64, M_TOT / 64), 256, 0, stream>>>(
        Y, W_out, b_out, out);
}

// Round 2
// 294.809 us; speedup vs baseline: 3.4252x; 3.4252x over previous
//
#include <hip/hip_runtime.h>
#include <math.h>

#define EMBED 1024
#define NH    16
#define DH    64
#define BATCH 2
#define SEQ   2048
#define MTOT  4096
#define BHTOT 32

typedef float f32x4 __attribute__((ext_vector_type(4)));
typedef short s16x8 __attribute__((ext_vector_type(8)));
typedef short s16x4 __attribute__((ext_vector_type(4)));

#define AS1 __attribute__((address_space(1)))
#define AS3 __attribute__((address_space(3)))

__device__ __forceinline__ unsigned short bf16_rne(float f) {
    unsigned u = __builtin_bit_cast(unsigned, f);
    return (unsigned short)((u + 0x7FFFu + ((u >> 16) & 1u)) >> 16);
}
__device__ __forceinline__ float bf16_f(unsigned short h) {
    unsigned u = ((unsigned)h) << 16;
    return __builtin_bit_cast(float, u);
}
__device__ __forceinline__ void split2(float v, unsigned short& hi, unsigned short& lo) {
    hi = bf16_rne(v);
    lo = bf16_rne(v - bf16_f(hi));
}
__device__ __forceinline__ void gload16(const void* g, void* l) {
    __builtin_amdgcn_global_load_lds((const AS1 void*)g, (AS3 void*)l, 16, 0, 0);
}
#define MFMA16(a, b, c) __builtin_amdgcn_mfma_f32_16x16x32_bf16((a), (b), (c), 0, 0, 0)

// ---------------------------------------------------------------------------
// splitT: W fp32 [Kd][Nd]  ->  HiT, LoT bf16 [Nd][Kd] (transposed + hi/lo split)
// ---------------------------------------------------------------------------
__global__ __launch_bounds__(256)
void splitT_kernel(const float* __restrict__ W, unsigned short* __restrict__ HiT,
                   unsigned short* __restrict__ LoT, int Kd, int Nd)
{
    __shared__ float T[32][33];
    const int tid = threadIdx.x;
    const int n0 = blockIdx.x * 32, k0 = blockIdx.y * 32;
    {
        const int row = tid >> 3, c4 = (tid & 7) * 4;
        float4 v = *(const float4*)&W[(size_t)(k0 + row) * Nd + n0 + c4];
        T[row][c4] = v.x; T[row][c4 + 1] = v.y; T[row][c4 + 2] = v.z; T[row][c4 + 3] = v.w;
    }
    __syncthreads();
    {
        const int nr = tid >> 3, c4 = (tid & 7) * 4;
        s16x4 h4, l4;
#pragma unroll
        for (int e = 0; e < 4; ++e) {
            unsigned short h, l;
            split2(T[c4 + e][nr], h, l);
            h4[e] = (short)h; l4[e] = (short)l;
        }
        *(s16x4*)&HiT[(size_t)(n0 + nr) * Kd + k0 + c4] = h4;
        *(s16x4*)&LoT[(size_t)(n0 + nr) * Kd + k0 + c4] = l4;
    }
}

// ---------------------------------------------------------------------------
// QKV GEMM: X fp32 [4096][1024] @ W^T-split bf16 [3072][1024] + bias
//   -> Qh/Ql/Kh/Kl [bh][t][64], Vh/Vl transposed [bh][64][t]   (Q scaled 0.125)
// 128x128 tile, BK=32, 4 waves, 3-combo split MFMA.
// ---------------------------------------------------------------------------
__global__ __launch_bounds__(256)
void qkv_gemm_kernel(const float* __restrict__ X, const unsigned short* __restrict__ BhT,
                     const unsigned short* __restrict__ BlT, const float* __restrict__ bias,
                     unsigned short* __restrict__ Qh, unsigned short* __restrict__ Ql,
                     unsigned short* __restrict__ Kh, unsigned short* __restrict__ Kl,
                     unsigned short* __restrict__ Vh, unsigned short* __restrict__ Vl)
{
    constexpr int KD = 1024;
    __shared__ __align__(16) short Ah[128 * 40], Al[128 * 40];   // padded pitch 40
    __shared__ __align__(16) short Bh[128 * 32], Bl[128 * 32];   // swizzled linear

    const int tid = threadIdx.x;
    const int lane = tid & 63, wid = tid >> 6;
    const int g = lane >> 4, ln = lane & 15;
    const int wm = wid >> 1, wn = wid & 1;
    const int m0 = blockIdx.y * 128, n0 = blockIdx.x * 128;

    f32x4 acc[4][4];
#pragma unroll
    for (int i = 0; i < 4; ++i)
#pragma unroll
        for (int j = 0; j < 4; ++j) acc[i][j] = (f32x4){0.f, 0.f, 0.f, 0.f};

    const int brow = lane >> 2;   // 0..15 row within a 1 KB staging instruction
    const int bs = lane & 3;      // stored chunk slot

    for (int k0 = 0; k0 < KD; k0 += 32) {
        __syncthreads();
        // stage A: fp32 -> hi/lo bf16, padded LDS
#pragma unroll
        for (int i = 0; i < 4; ++i) {
            int idx = tid + i * 256;
            int row = idx >> 3, c4 = (idx & 7) * 4;
            float4 x4 = *(const float4*)&X[(size_t)(m0 + row) * KD + k0 + c4];
            float xv[4] = {x4.x, x4.y, x4.z, x4.w};
            s16x4 h4, l4;
#pragma unroll
            for (int e = 0; e < 4; ++e) {
                unsigned short h, l; split2(xv[e], h, l);
                h4[e] = (short)h; l4[e] = (short)l;
            }
            *(s16x4*)&Ah[row * 40 + c4] = h4;
            *(s16x4*)&Al[row * 40 + c4] = l4;
        }
        // stage B: global_load_lds, source pre-swizzled (chunk ^= (row>>1)&3)
        {
            const unsigned short* gsrc = (wid < 2) ? BhT : BlT;
            short* ldst = (wid < 2) ? Bh : Bl;
            int jb = (wid & 1) * 4;
#pragma unroll
            for (int a = 0; a < 4; ++a) {
                int j = jb + a;
                int row_loc = j * 16 + brow;
                int kc = bs ^ ((row_loc >> 1) & 3);
                gload16(gsrc + (size_t)(n0 + row_loc) * KD + k0 + kc * 8, ldst + j * 512);
            }
        }
        __syncthreads();

        s16x8 fah[4], fal[4], fbh[4], fbl[4];
#pragma unroll
        for (int am = 0; am < 4; ++am) {
            int m_loc = wm * 64 + am * 16 + ln;
            const short* pa = &Ah[m_loc * 40 + g * 8];
            s16x4 a0 = *(const s16x4*)pa, a1 = *(const s16x4*)(pa + 4);
            fah[am] = __builtin_shufflevector(a0, a1, 0, 1, 2, 3, 4, 5, 6, 7);
            const short* pb = &Al[m_loc * 40 + g * 8];
            s16x4 b0 = *(const s16x4*)pb, b1 = *(const s16x4*)(pb + 4);
            fal[am] = __builtin_shufflevector(b0, b1, 0, 1, 2, 3, 4, 5, 6, 7);
        }
#pragma unroll
        for (int bn = 0; bn < 4; ++bn) {
            int n_loc = wn * 64 + bn * 16 + ln;
            int sl = (g ^ ((n_loc >> 1) & 3)) * 8;
            fbh[bn] = *(const s16x8*)&Bh[n_loc * 32 + sl];
            fbl[bn] = *(const s16x8*)&Bl[n_loc * 32 + sl];
        }
#pragma unroll
        for (int am = 0; am < 4; ++am)
#pragma unroll
            for (int bn = 0; bn < 4; ++bn) {
                acc[am][bn] = MFMA16(fah[am], fbh[bn], acc[am][bn]);
                acc[am][bn] = MFMA16(fah[am], fbl[bn], acc[am][bn]);
                acc[am][bn] = MFMA16(fal[am], fbh[bn], acc[am][bn]);
            }
    }

    // epilogue: bias + split scatter (C/D: row=(lane>>4)*4+r, col=lane&15)
#pragma unroll
    for (int am = 0; am < 4; ++am)
#pragma unroll
        for (int bn = 0; bn < 4; ++bn) {
            int n = n0 + wn * 64 + bn * 16 + ln;
            float bv = bias[n];
            int sec = n >> 10, cc = n & 1023, h = cc >> 6, d = cc & 63;
#pragma unroll
            for (int r = 0; r < 4; ++r) {
                int m = m0 + wm * 64 + am * 16 + g * 4 + r;
                int bb = m >> 11, t = m & 2047;
                int bh_i = bb * NH + h;
                float val = acc[am][bn][r] + bv;
                unsigned short hi, lo;
                if (sec == 0) {
                    val *= 0.125f; split2(val, hi, lo);
                    size_t idx = ((size_t)bh_i * SEQ + t) * DH + d;
                    Qh[idx] = hi; Ql[idx] = lo;
                } else if (sec == 1) {
                    split2(val, hi, lo);
                    size_t idx = ((size_t)bh_i * SEQ + t) * DH + d;
                    Kh[idx] = hi; Kl[idx] = lo;
                } else {
                    split2(val, hi, lo);
                    size_t idx = ((size_t)bh_i * DH + d) * SEQ + t;   // V transposed
                    Vh[idx] = hi; Vl[idx] = lo;
                }
            }
        }
}

// ---------------------------------------------------------------------------
// Attention: per (bh, 64-row q-tile). 4 waves x 16 q-rows. Split MFMA for
// QK^T and PV, fp32 online softmax. K/V tiles via swizzled global_load_lds;
// P aliases the K LDS region.
// ---------------------------------------------------------------------------
__global__ __launch_bounds__(256)
void attn_kernel(const unsigned short* __restrict__ Qh_g, const unsigned short* __restrict__ Ql_g,
                 const unsigned short* __restrict__ Kh_g, const unsigned short* __restrict__ Kl_g,
                 const unsigned short* __restrict__ Vh_g, const unsigned short* __restrict__ Vl_g,
                 unsigned short* __restrict__ Yh, unsigned short* __restrict__ Yl)
{
    __shared__ __align__(16) short Qs_h[64 * 72], Qs_l[64 * 72];   // padded pitch 72
    __shared__ __align__(16) short KPh[64 * 64], KPl[64 * 64];     // K tile, then P
    __shared__ __align__(16) short Vth[64 * 64], Vtl[64 * 64];     // V^T tile

    const int tid = threadIdx.x, lane = tid & 63, wid = tid >> 6;
    const int g = lane >> 4, ln = lane & 15;
    const int bid = blockIdx.x;
    const int qt = 31 - (bid >> 5), bh = bid & 31;   // heavy q-tiles dispatch first

    // stage Q once (reg-staged into padded LDS)
    {
        const size_t qoff = ((size_t)bh * SEQ + qt * 64) * DH;
#pragma unroll
        for (int i = 0; i < 2; ++i) {
            int s = tid + i * 256;
            int row = s >> 3, c = s & 7;
            *(s16x8*)&Qs_h[row * 72 + c * 8] = *(const s16x8*)&Qh_g[qoff + row * 64 + c * 8];
            *(s16x8*)&Qs_l[row * 72 + c * 8] = *(const s16x8*)&Ql_g[qoff + row * 64 + c * 8];
        }
    }

    float m_i[4], l_i[4];
    f32x4 yacc[4];
#pragma unroll
    for (int r = 0; r < 4; ++r) { m_i[r] = -INFINITY; l_i[r] = 0.f; }
#pragma unroll
    for (int f = 0; f < 4; ++f) yacc[f] = (f32x4){0.f, 0.f, 0.f, 0.f};

    const int qbase = wid * 16;
    const int srow = lane >> 3, ss = lane & 7;

    for (int kt = 0; kt <= qt; ++kt) {
        __syncthreads();   // prior tile's reads (and Q stage) complete
        // stage K/V: wave w owns one of {Kh,Kl,Vh,Vl}; chunk ^= row&7 swizzle
        {
            const unsigned short* gb;
            short* lb;
            if (wid == 0) { gb = Kh_g; lb = KPh; }
            else if (wid == 1) { gb = Kl_g; lb = KPl; }
            else if (wid == 2) { gb = Vh_g; lb = Vth; }
            else { gb = Vl_g; lb = Vtl; }
            const bool isK = (wid < 2);
#pragma unroll
            for (int j = 0; j < 8; ++j) {
                int row = j * 8 + srow;
                int kc = ss ^ (row & 7);
                const unsigned short* src = isK
                    ? gb + ((size_t)bh * SEQ + kt * 64 + row) * DH + kc * 8
                    : gb + ((size_t)bh * DH + row) * SEQ + kt * 64 + kc * 8;
                gload16(src, lb + j * 512);
            }
        }
        __syncthreads();

        // ---- scores S = Q.K^T (3-combo split)
        f32x4 s4[4];
#pragma unroll
        for (int f = 0; f < 4; ++f) s4[f] = (f32x4){0.f, 0.f, 0.f, 0.f};
#pragma unroll
        for (int h2 = 0; h2 < 2; ++h2) {
            int c = h2 * 4 + g;
            s16x8 qh = *(const s16x8*)&Qs_h[(qbase + ln) * 72 + c * 8];
            s16x8 ql = *(const s16x8*)&Qs_l[(qbase + ln) * 72 + c * 8];
#pragma unroll
            for (int kf = 0; kf < 4; ++kf) {
                int nl = kf * 16 + ln;
                int sl = (c ^ (nl & 7)) * 8;
                s16x8 kh = *(const s16x8*)&KPh[nl * 64 + sl];
                s16x8 kl = *(const s16x8*)&KPl[nl * 64 + sl];
                s4[kf] = MFMA16(qh, kh, s4[kf]);
                s4[kf] = MFMA16(qh, kl, s4[kf]);
                s4[kf] = MFMA16(ql, kh, s4[kf]);
            }
        }

        if (kt == qt) {   // causal mask on diagonal tile
#pragma unroll
            for (int kf = 0; kf < 4; ++kf)
#pragma unroll
                for (int r = 0; r < 4; ++r)
                    if (kf * 16 + ln > qbase + g * 4 + r) s4[kf][r] = -INFINITY;
        }

        // ---- online softmax (rows = qbase + g*4 + r; 16-lane k-reduce)
        float p[4][4], alpha[4];
#pragma unroll
        for (int r = 0; r < 4; ++r) {
            float mx = fmaxf(fmaxf(s4[0][r], s4[1][r]), fmaxf(s4[2][r], s4[3][r]));
            mx = fmaxf(mx, __shfl_xor(mx, 1));
            mx = fmaxf(mx, __shfl_xor(mx, 2));
            mx = fmaxf(mx, __shfl_xor(mx, 4));
            mx = fmaxf(mx, __shfl_xor(mx, 8));
            float mn = fmaxf(m_i[r], mx);
            float al = __expf(m_i[r] - mn);
            float ls = 0.f;
#pragma unroll
            for (int kf = 0; kf < 4; ++kf) { p[kf][r] = __expf(s4[kf][r] - mn); ls += p[kf][r]; }
            ls += __shfl_xor(ls, 1); ls += __shfl_xor(ls, 2);
            ls += __shfl_xor(ls, 4); ls += __shfl_xor(ls, 8);
            l_i[r] = l_i[r] * al + ls;
            m_i[r] = mn;
            alpha[r] = al;
        }
#pragma unroll
        for (int f = 0; f < 4; ++f)
#pragma unroll
            for (int r = 0; r < 4; ++r) yacc[f][r] *= alpha[r];

        __syncthreads();   // all waves done reading K tiles
        // write split P over the K region (same chunk^row&7 swizzle)
#pragma unroll
        for (int kf = 0; kf < 4; ++kf)
#pragma unroll
            for (int r = 0; r < 4; ++r) {
                int row = qbase + g * 4 + r;
                int col = kf * 16 + ln;
                int st = (col >> 3) ^ (row & 7), e = col & 7;
                unsigned short hi, lo; split2(p[kf][r], hi, lo);
                KPh[row * 64 + st * 8 + e] = (short)hi;
                KPl[row * 64 + st * 8 + e] = (short)lo;
            }
        __syncthreads();

        // ---- PV (3-combo split); B-operand = V^T rows (d), chunks = keys
#pragma unroll
        for (int h2 = 0; h2 < 2; ++h2) {
            int c = h2 * 4 + g;
            int prow = qbase + ln;
            int psl = (c ^ (prow & 7)) * 8;
            s16x8 ph = *(const s16x8*)&KPh[prow * 64 + psl];
            s16x8 pl = *(const s16x8*)&KPl[prow * 64 + psl];
#pragma unroll
            for (int df = 0; df < 4; ++df) {
                int vrow = df * 16 + ln;
                int vsl = (c ^ (vrow & 7)) * 8;
                s16x8 vh = *(const s16x8*)&Vth[vrow * 64 + vsl];
                s16x8 vl = *(const s16x8*)&Vtl[vrow * 64 + vsl];
                yacc[df] = MFMA16(ph, vh, yacc[df]);
                yacc[df] = MFMA16(ph, vl, yacc[df]);
                yacc[df] = MFMA16(pl, vh, yacc[df]);
            }
        }
    }

    // epilogue: normalize, split, write Y (row-major [B*T][C], C-col = h*64+d)
    const int b = bh >> 4, h = bh & 15;
#pragma unroll
    for (int df = 0; df < 4; ++df)
#pragma unroll
        for (int r = 0; r < 4; ++r) {
            float val = yacc[df][r] / l_i[r];
            int q = qt * 64 + qbase + g * 4 + r;
            int col = h * DH + df * 16 + ln;
            unsigned short hi, lo; split2(val, hi, lo);
            size_t idx = ((size_t)(b * SEQ + q)) * EMBED + col;
            Yh[idx] = hi; Yl[idx] = lo;
        }
}

// ---------------------------------------------------------------------------
// Out GEMM: Y-split bf16 [4096][1024] @ Wout^T-split bf16 [1024][1024] + bias
// Both operands via swizzled global_load_lds; fp32 output.
// ---------------------------------------------------------------------------
__global__ __launch_bounds__(256)
void out_gemm_kernel(const unsigned short* __restrict__ Yh_g, const unsigned short* __restrict__ Yl_g,
                     const unsigned short* __restrict__ WhT, const unsigned short* __restrict__ WlT,
                     const float* __restrict__ bias, float* __restrict__ out)
{
    constexpr int KD = 1024, ND = 1024;
    __shared__ __align__(16) short Ah[128 * 32], Al[128 * 32];
    __shared__ __align__(16) short Bh[128 * 32], Bl[128 * 32];

    const int tid = threadIdx.x, lane = tid & 63, wid = tid >> 6;
    const int g = lane >> 4, ln = lane & 15;
    const int wm = wid >> 1, wn = wid & 1;
    const int m0 = blockIdx.y * 128, n0 = blockIdx.x * 128;

    f32x4 acc[4][4];
#pragma unroll
    for (int i = 0; i < 4; ++i)
#pragma unroll
        for (int j = 0; j < 4; ++j) acc[i][j] = (f32x4){0.f, 0.f, 0.f, 0.f};

    const int srow = lane >> 2, ss = lane & 3;

    for (int k0 = 0; k0 < KD; k0 += 32) {
        __syncthreads();
        {
            const unsigned short* gb;
            short* lb;
            int roff;
            if (wid == 0) { gb = Yh_g; lb = Ah; roff = m0; }
            else if (wid == 1) { gb = Yl_g; lb = Al; roff = m0; }
            else if (wid == 2) { gb = WhT; lb = Bh; roff = n0; }
            else { gb = WlT; lb = Bl; roff = n0; }
#pragma unroll
            for (int j = 0; j < 8; ++j) {
                int row_loc = j * 16 + srow;
                int kc = ss ^ ((row_loc >> 1) & 3);
                gload16(gb + (size_t)(roff + row_loc) * KD + k0 + kc * 8, lb + j * 512);
            }
        }
        __syncthreads();

        s16x8 fah[4], fal[4], fbh[4], fbl[4];
#pragma unroll
        for (int am = 0; am < 4; ++am) {
            int m_loc = wm * 64 + am * 16 + ln;
            int sl = (g ^ ((m_loc >> 1) & 3)) * 8;
            fah[am] = *(const s16x8*)&Ah[m_loc * 32 + sl];
            fal[am] = *(const s16x8*)&Al[m_loc * 32 + sl];
        }
#pragma unroll
        for (int bn = 0; bn < 4; ++bn) {
            int n_loc = wn * 64 + bn * 16 + ln;
            int sl = (g ^ ((n_loc >> 1) & 3)) * 8;
            fbh[bn] = *(const s16x8*)&Bh[n_loc * 32 + sl];
            fbl[bn] = *(const s16x8*)&Bl[n_loc * 32 + sl];
        }
#pragma unroll
        for (int am = 0; am < 4; ++am)
#pragma unroll
            for (int bn = 0; bn < 4; ++bn) {
                acc[am][bn] = MFMA16(fah[am], fbh[bn], acc[am][bn]);
                acc[am][bn] = MFMA16(fah[am], fbl[bn], acc[am][bn]);
                acc[am][bn] = MFMA16(fal[am], fbh[bn], acc[am][bn]);
            }
    }

#pragma unroll
    for (int am = 0; am < 4; ++am)
#pragma unroll
        for (int bn = 0; bn < 4; ++bn) {
            int n = n0 + wn * 64 + bn * 16 + ln;
            float bv = bias[n];
#pragma unroll
            for (int r = 0; r < 4; ++r) {
                int m = m0 + wm * 64 + am * 16 + g * 4 + r;
                out[(size_t)m * ND + n] = acc[am][bn][r] + bv;
            }
        }
}

// ---------------------------------------------------------------------------
extern "C" void kernel_launch(void* const* d_in, const int* in_sizes, int n_in,
                              void* d_out, int out_size, void* d_ws, size_t ws_size,
                              hipStream_t stream)
{
    const float* x     = (const float*)d_in[0];
    const float* W_kqv = (const float*)d_in[1];
    const float* b_kqv = (const float*)d_in[2];
    const float* W_out = (const float*)d_in[3];
    const float* b_out = (const float*)d_in[4];
    float* out = (float*)d_out;

    char* ws = (char*)d_ws;
    const size_t MB = 1024 * 1024;
    // [0,48MB): Q/K/V hi+lo bf16 (V transposed). After attn: [0,4MB) = Wout^T parts.
    unsigned short* Qh = (unsigned short*)(ws);
    unsigned short* Ql = Qh + 4194304;
    unsigned short* Kh = Ql + 4194304;
    unsigned short* Kl = Kh + 4194304;
    unsigned short* Vh = Kl + 4194304;
    unsigned short* Vl = Vh + 4194304;
    // [48MB,60MB): Wkqv^T parts during GEMM1; then [48MB,64MB): Y parts.
    unsigned short* WhT = (unsigned short*)(ws + 48 * MB);
    unsigned short* WlT = WhT + 3145728;
    unsigned short* Yh  = (unsigned short*)(ws + 48 * MB);
    unsigned short* Yl  = Yh + 4194304;
    unsigned short* WoTh = (unsigned short*)(ws);
    unsigned short* WoTl = WoTh + 1048576;

    splitT_kernel<<<dim3(3 * EMBED / 32, EMBED / 32), 256, 0, stream>>>(
        W_kqv, WhT, WlT, EMBED, 3 * EMBED);
    qkv_gemm_kernel<<<dim3(3 * EMBED / 128, MTOT / 128), 256, 0, stream>>>(
        x, WhT, WlT, b_kqv, Qh, Ql, Kh, Kl, Vh, Vl);
    attn_kernel<<<dim3(BHTOT * (SEQ / 64)), 256, 0, stream>>>(
        Qh, Ql, Kh, Kl, Vh, Vl, Yh, Yl);
    splitT_kernel<<<dim3(EMBED / 32, EMBED / 32), 256, 0, stream>>>(
        W_out, WoTh, WoTl, EMBED, EMBED);
    out_gemm_kernel<<<dim3(EMBED / 128, MTOT / 128), 256, 0, stream>>>(
        Yh, Yl, WoTh, WoTl, b_out, out);
}

// Round 4
// 253.044 us; speedup vs baseline: 3.9905x; 1.1651x over previous
//
#include <hip/hip_runtime.h>
#include <math.h>

#define EMBED 1024
#define NH    16
#define DH    64
#define BATCH 2
#define SEQ   2048
#define MTOT  4096
#define BHTOT 32

typedef float f32x4 __attribute__((ext_vector_type(4)));
typedef short s16x8 __attribute__((ext_vector_type(8)));
typedef short s16x4 __attribute__((ext_vector_type(4)));

#define AS1 __attribute__((address_space(1)))
#define AS3 __attribute__((address_space(3)))

__device__ __forceinline__ unsigned short bf16_rne(float f) {
    unsigned u = __builtin_bit_cast(unsigned, f);
    return (unsigned short)((u + 0x7FFFu + ((u >> 16) & 1u)) >> 16);
}
__device__ __forceinline__ float bf16_f(unsigned short h) {
    unsigned u = ((unsigned)h) << 16;
    return __builtin_bit_cast(float, u);
}
__device__ __forceinline__ void split2(float v, unsigned short& hi, unsigned short& lo) {
    hi = bf16_rne(v);
    lo = bf16_rne(v - bf16_f(hi));
}
__device__ __forceinline__ void gload16(const void* g, void* l) {
    __builtin_amdgcn_global_load_lds((const AS1 void*)g, (AS3 void*)l, 16, 0, 0);
}
#define MFMA16(a, b, c) __builtin_amdgcn_mfma_f32_16x16x32_bf16((a), (b), (c), 0, 0, 0)

// ---------------------------------------------------------------------------
// splitX: X fp32 [M][K] -> Xh, Xl bf16 (same layout, hi/lo split)
// ---------------------------------------------------------------------------
__global__ __launch_bounds__(256)
void splitX_kernel(const float* __restrict__ X, unsigned short* __restrict__ Xh,
                   unsigned short* __restrict__ Xl)
{
    const size_t i = ((size_t)blockIdx.x * 256 + threadIdx.x) * 8;
    float4 a = *(const float4*)&X[i];
    float4 b = *(const float4*)&X[i + 4];
    float v[8] = {a.x, a.y, a.z, a.w, b.x, b.y, b.z, b.w};
    s16x8 h8, l8;
#pragma unroll
    for (int e = 0; e < 8; ++e) {
        unsigned short h, l; split2(v[e], h, l);
        h8[e] = (short)h; l8[e] = (short)l;
    }
    *(s16x8*)&Xh[i] = h8;
    *(s16x8*)&Xl[i] = l8;
}

// ---------------------------------------------------------------------------
// splitT: W fp32 [Kd][Nd]  ->  HiT, LoT bf16 [Nd][Kd] (transposed + hi/lo split)
// ---------------------------------------------------------------------------
__global__ __launch_bounds__(256)
void splitT_kernel(const float* __restrict__ W, unsigned short* __restrict__ HiT,
                   unsigned short* __restrict__ LoT, int Kd, int Nd)
{
    __shared__ float T[32][33];
    const int tid = threadIdx.x;
    const int n0 = blockIdx.x * 32, k0 = blockIdx.y * 32;
    {
        const int row = tid >> 3, c4 = (tid & 7) * 4;
        float4 v = *(const float4*)&W[(size_t)(k0 + row) * Nd + n0 + c4];
        T[row][c4] = v.x; T[row][c4 + 1] = v.y; T[row][c4 + 2] = v.z; T[row][c4 + 3] = v.w;
    }
    __syncthreads();
    {
        const int nr = tid >> 3, c4 = (tid & 7) * 4;
        s16x4 h4, l4;
#pragma unroll
        for (int e = 0; e < 4; ++e) {
            unsigned short h, l;
            split2(T[c4 + e][nr], h, l);
            h4[e] = (short)h; l4[e] = (short)l;
        }
        *(s16x4*)&HiT[(size_t)(n0 + nr) * Kd + k0 + c4] = h4;
        *(s16x4*)&LoT[(size_t)(n0 + nr) * Kd + k0 + c4] = l4;
    }
}

// ---------------------------------------------------------------------------
// QKV GEMM (all-bf16): Xsplit [4096][1024] @ Wkqv^T-split [3072][1024] + bias
//   -> Qh/Ql/Kh/Kl [bh][t][64], Vh/Vl transposed [bh][64][t]  (Q scaled 0.125)
// 128x128 tile, BK=32, 4 waves; all 4 tiles staged via swizzled global_load_lds.
// ---------------------------------------------------------------------------
__global__ __launch_bounds__(256)
void qkv_gemm_kernel(const unsigned short* __restrict__ Xh_g, const unsigned short* __restrict__ Xl_g,
                     const unsigned short* __restrict__ BhT, const unsigned short* __restrict__ BlT,
                     const float* __restrict__ bias,
                     unsigned short* __restrict__ Qh, unsigned short* __restrict__ Ql,
                     unsigned short* __restrict__ Kh, unsigned short* __restrict__ Kl,
                     unsigned short* __restrict__ Vh, unsigned short* __restrict__ Vl)
{
    constexpr int KD = 1024;
    __shared__ __align__(16) short Ah[128 * 32], Al[128 * 32];
    __shared__ __align__(16) short Bh[128 * 32], Bl[128 * 32];

    const int tid = threadIdx.x, lane = tid & 63, wid = tid >> 6;
    const int g = lane >> 4, ln = lane & 15;
    const int wm = wid >> 1, wn = wid & 1;
    const int m0 = blockIdx.y * 128, n0 = blockIdx.x * 128;

    f32x4 acc[4][4];
#pragma unroll
    for (int i = 0; i < 4; ++i)
#pragma unroll
        for (int j = 0; j < 4; ++j) acc[i][j] = (f32x4){0.f, 0.f, 0.f, 0.f};

    const int srow = lane >> 2, ss = lane & 3;

    for (int k0 = 0; k0 < KD; k0 += 32) {
        __syncthreads();
        {
            const unsigned short* gb;
            short* lb;
            int roff;
            if (wid == 0) { gb = Xh_g; lb = Ah; roff = m0; }
            else if (wid == 1) { gb = Xl_g; lb = Al; roff = m0; }
            else if (wid == 2) { gb = BhT; lb = Bh; roff = n0; }
            else { gb = BlT; lb = Bl; roff = n0; }
#pragma unroll
            for (int j = 0; j < 8; ++j) {
                int row_loc = j * 16 + srow;
                int kc = ss ^ ((row_loc >> 1) & 3);
                gload16(gb + (size_t)(roff + row_loc) * KD + k0 + kc * 8, lb + j * 512);
            }
        }
        __syncthreads();

        s16x8 fah[4], fal[4], fbh[4], fbl[4];
#pragma unroll
        for (int am = 0; am < 4; ++am) {
            int m_loc = wm * 64 + am * 16 + ln;
            int sl = (g ^ ((m_loc >> 1) & 3)) * 8;
            fah[am] = *(const s16x8*)&Ah[m_loc * 32 + sl];
            fal[am] = *(const s16x8*)&Al[m_loc * 32 + sl];
        }
#pragma unroll
        for (int bn = 0; bn < 4; ++bn) {
            int n_loc = wn * 64 + bn * 16 + ln;
            int sl = (g ^ ((n_loc >> 1) & 3)) * 8;
            fbh[bn] = *(const s16x8*)&Bh[n_loc * 32 + sl];
            fbl[bn] = *(const s16x8*)&Bl[n_loc * 32 + sl];
        }
#pragma unroll
        for (int am = 0; am < 4; ++am)
#pragma unroll
            for (int bn = 0; bn < 4; ++bn) {
                acc[am][bn] = MFMA16(fah[am], fbh[bn], acc[am][bn]);
                acc[am][bn] = MFMA16(fah[am], fbl[bn], acc[am][bn]);
                acc[am][bn] = MFMA16(fal[am], fbh[bn], acc[am][bn]);
            }
    }

    // epilogue: bias + split scatter (C/D: row=(lane>>4)*4+r, col=lane&15)
#pragma unroll
    for (int am = 0; am < 4; ++am)
#pragma unroll
        for (int bn = 0; bn < 4; ++bn) {
            int n = n0 + wn * 64 + bn * 16 + ln;
            float bv = bias[n];
            int sec = n >> 10, cc = n & 1023, h = cc >> 6, d = cc & 63;
#pragma unroll
            for (int r = 0; r < 4; ++r) {
                int m = m0 + wm * 64 + am * 16 + g * 4 + r;
                int bb = m >> 11, t = m & 2047;
                int bh_i = bb * NH + h;
                float val = acc[am][bn][r] + bv;
                unsigned short hi, lo;
                if (sec == 0) {
                    val *= 0.125f; split2(val, hi, lo);
                    size_t idx = ((size_t)bh_i * SEQ + t) * DH + d;
                    Qh[idx] = hi; Ql[idx] = lo;
                } else if (sec == 1) {
                    split2(val, hi, lo);
                    size_t idx = ((size_t)bh_i * SEQ + t) * DH + d;
                    Kh[idx] = hi; Kl[idx] = lo;
                } else {
                    split2(val, hi, lo);
                    size_t idx = ((size_t)bh_i * DH + d) * SEQ + t;   // V transposed
                    Vh[idx] = hi; Vl[idx] = lo;
                }
            }
        }
}

// ---------------------------------------------------------------------------
// Attention: per (bh, 64-row q-tile). 4 waves x 16 q-rows. Split MFMA for
// QK^T and PV, fp32 online softmax. K/V tiles via swizzled global_load_lds;
// P aliases the K LDS region.
// ---------------------------------------------------------------------------
__global__ __launch_bounds__(256)
void attn_kernel(const unsigned short* __restrict__ Qh_g, const unsigned short* __restrict__ Ql_g,
                 const unsigned short* __restrict__ Kh_g, const unsigned short* __restrict__ Kl_g,
                 const unsigned short* __restrict__ Vh_g, const unsigned short* __restrict__ Vl_g,
                 unsigned short* __restrict__ Yh, unsigned short* __restrict__ Yl)
{
    __shared__ __align__(16) short Qs_h[64 * 72], Qs_l[64 * 72];   // padded pitch 72
    __shared__ __align__(16) short KPh[64 * 64], KPl[64 * 64];     // K tile, then P
    __shared__ __align__(16) short Vth[64 * 64], Vtl[64 * 64];     // V^T tile

    const int tid = threadIdx.x, lane = tid & 63, wid = tid >> 6;
    const int g = lane >> 4, ln = lane & 15;
    const int bid = blockIdx.x;
    const int qt = 31 - (bid >> 5), bh = bid & 31;   // heavy q-tiles dispatch first

    // stage Q once (reg-staged into padded LDS)
    {
        const size_t qoff = ((size_t)bh * SEQ + qt * 64) * DH;
#pragma unroll
        for (int i = 0; i < 2; ++i) {
            int s = tid + i * 256;
            int row = s >> 3, c = s & 7;
            *(s16x8*)&Qs_h[row * 72 + c * 8] = *(const s16x8*)&Qh_g[qoff + row * 64 + c * 8];
            *(s16x8*)&Qs_l[row * 72 + c * 8] = *(const s16x8*)&Ql_g[qoff + row * 64 + c * 8];
        }
    }

    float m_i[4], l_i[4];
    f32x4 yacc[4];
#pragma unroll
    for (int r = 0; r < 4; ++r) { m_i[r] = -INFINITY; l_i[r] = 0.f; }
#pragma unroll
    for (int f = 0; f < 4; ++f) yacc[f] = (f32x4){0.f, 0.f, 0.f, 0.f};

    const int qbase = wid * 16;
    const int srow = lane >> 3, ss = lane & 7;

    for (int kt = 0; kt <= qt; ++kt) {
        __syncthreads();   // prior tile's reads (and Q stage) complete
        // stage K/V: wave w owns one of {Kh,Kl,Vh,Vl}; chunk ^= row&7 swizzle
        {
            const unsigned short* gb;
            short* lb;
            if (wid == 0) { gb = Kh_g; lb = KPh; }
            else if (wid == 1) { gb = Kl_g; lb = KPl; }
            else if (wid == 2) { gb = Vh_g; lb = Vth; }
            else { gb = Vl_g; lb = Vtl; }
            const bool isK = (wid < 2);
#pragma unroll
            for (int j = 0; j < 8; ++j) {
                int row = j * 8 + srow;
                int kc = ss ^ (row & 7);
                const unsigned short* src = isK
                    ? gb + ((size_t)bh * SEQ + kt * 64 + row) * DH + kc * 8
                    : gb + ((size_t)bh * DH + row) * SEQ + kt * 64 + kc * 8;
                gload16(src, lb + j * 512);
            }
        }
        __syncthreads();

        // ---- scores S = Q.K^T (3-combo split)
        f32x4 s4[4];
#pragma unroll
        for (int f = 0; f < 4; ++f) s4[f] = (f32x4){0.f, 0.f, 0.f, 0.f};
#pragma unroll
        for (int h2 = 0; h2 < 2; ++h2) {
            int c = h2 * 4 + g;
            s16x8 qh = *(const s16x8*)&Qs_h[(qbase + ln) * 72 + c * 8];
            s16x8 ql = *(const s16x8*)&Qs_l[(qbase + ln) * 72 + c * 8];
#pragma unroll
            for (int kf = 0; kf < 4; ++kf) {
                int nl = kf * 16 + ln;
                int sl = (c ^ (nl & 7)) * 8;
                s16x8 kh = *(const s16x8*)&KPh[nl * 64 + sl];
                s16x8 kl = *(const s16x8*)&KPl[nl * 64 + sl];
                s4[kf] = MFMA16(qh, kh, s4[kf]);
                s4[kf] = MFMA16(qh, kl, s4[kf]);
                s4[kf] = MFMA16(ql, kh, s4[kf]);
            }
        }

        if (kt == qt) {   // causal mask on diagonal tile
#pragma unroll
            for (int kf = 0; kf < 4; ++kf)
#pragma unroll
                for (int r = 0; r < 4; ++r)
                    if (kf * 16 + ln > qbase + g * 4 + r) s4[kf][r] = -INFINITY;
        }

        // ---- online softmax (rows = qbase + g*4 + r; 16-lane k-reduce)
        float p[4][4], alpha[4];
#pragma unroll
        for (int r = 0; r < 4; ++r) {
            float mx = fmaxf(fmaxf(s4[0][r], s4[1][r]), fmaxf(s4[2][r], s4[3][r]));
            mx = fmaxf(mx, __shfl_xor(mx, 1));
            mx = fmaxf(mx, __shfl_xor(mx, 2));
            mx = fmaxf(mx, __shfl_xor(mx, 4));
            mx = fmaxf(mx, __shfl_xor(mx, 8));
            float mn = fmaxf(m_i[r], mx);
            float al = __expf(m_i[r] - mn);
            float ls = 0.f;
#pragma unroll
            for (int kf = 0; kf < 4; ++kf) { p[kf][r] = __expf(s4[kf][r] - mn); ls += p[kf][r]; }
            ls += __shfl_xor(ls, 1); ls += __shfl_xor(ls, 2);
            ls += __shfl_xor(ls, 4); ls += __shfl_xor(ls, 8);
            l_i[r] = l_i[r] * al + ls;
            m_i[r] = mn;
            alpha[r] = al;
        }
#pragma unroll
        for (int f = 0; f < 4; ++f)
#pragma unroll
            for (int r = 0; r < 4; ++r) yacc[f][r] *= alpha[r];

        __syncthreads();   // all waves done reading K tiles
        // write split P over the K region (same chunk^row&7 swizzle)
#pragma unroll
        for (int kf = 0; kf < 4; ++kf)
#pragma unroll
            for (int r = 0; r < 4; ++r) {
                int row = qbase + g * 4 + r;
                int col = kf * 16 + ln;
                int st = (col >> 3) ^ (row & 7), e = col & 7;
                unsigned short hi, lo; split2(p[kf][r], hi, lo);
                KPh[row * 64 + st * 8 + e] = (short)hi;
                KPl[row * 64 + st * 8 + e] = (short)lo;
            }
        __syncthreads();

        // ---- PV (3-combo split); B-operand = V^T rows (d), chunks = keys
#pragma unroll
        for (int h2 = 0; h2 < 2; ++h2) {
            int c = h2 * 4 + g;
            int prow = qbase + ln;
            int psl = (c ^ (prow & 7)) * 8;
            s16x8 ph = *(const s16x8*)&KPh[prow * 64 + psl];
            s16x8 pl = *(const s16x8*)&KPl[prow * 64 + psl];
#pragma unroll
            for (int df = 0; df < 4; ++df) {
                int vrow = df * 16 + ln;
                int vsl = (c ^ (vrow & 7)) * 8;
                s16x8 vh = *(const s16x8*)&Vth[vrow * 64 + vsl];
                s16x8 vl = *(const s16x8*)&Vtl[vrow * 64 + vsl];
                yacc[df] = MFMA16(ph, vh, yacc[df]);
                yacc[df] = MFMA16(ph, vl, yacc[df]);
                yacc[df] = MFMA16(pl, vh, yacc[df]);
            }
        }
    }

    // epilogue: normalize, split, write Y (row-major [B*T][C], C-col = h*64+d)
    const int b = bh >> 4, h = bh & 15;
#pragma unroll
    for (int df = 0; df < 4; ++df)
#pragma unroll
        for (int r = 0; r < 4; ++r) {
            float val = yacc[df][r] / l_i[r];
            int q = qt * 64 + qbase + g * 4 + r;
            int col = h * DH + df * 16 + ln;
            unsigned short hi, lo; split2(val, hi, lo);
            size_t idx = ((size_t)(b * SEQ + q)) * EMBED + col;
            Yh[idx] = hi; Yl[idx] = lo;
        }
}

// ---------------------------------------------------------------------------
// Out GEMM: Y-split bf16 [4096][1024] @ Wout^T-split bf16 [1024][1024] + bias
// Both operands via swizzled global_load_lds; fp32 output.
// ---------------------------------------------------------------------------
__global__ __launch_bounds__(256)
void out_gemm_kernel(const unsigned short* __restrict__ Yh_g, const unsigned short* __restrict__ Yl_g,
                     const unsigned short* __restrict__ WhT, const unsigned short* __restrict__ WlT,
                     const float* __restrict__ bias, float* __restrict__ out)
{
    constexpr int KD = 1024, ND = 1024;
    __shared__ __align__(16) short Ah[128 * 32], Al[128 * 32];
    __shared__ __align__(16) short Bh[128 * 32], Bl[128 * 32];

    const int tid = threadIdx.x, lane = tid & 63, wid = tid >> 6;
    const int g = lane >> 4, ln = lane & 15;
    const int wm = wid >> 1, wn = wid & 1;
    const int m0 = blockIdx.y * 128, n0 = blockIdx.x * 128;

    f32x4 acc[4][4];
#pragma unroll
    for (int i = 0; i < 4; ++i)
#pragma unroll
        for (int j = 0; j < 4; ++j) acc[i][j] = (f32x4){0.f, 0.f, 0.f, 0.f};

    const int srow = lane >> 2, ss = lane & 3;

    for (int k0 = 0; k0 < KD; k0 += 32) {
        __syncthreads();
        {
            const unsigned short* gb;
            short* lb;
            int roff;
            if (wid == 0) { gb = Yh_g; lb = Ah; roff = m0; }
            else if (wid == 1) { gb = Yl_g; lb = Al; roff = m0; }
            else if (wid == 2) { gb = WhT; lb = Bh; roff = n0; }
            else { gb = WlT; lb = Bl; roff = n0; }
#pragma unroll
            for (int j = 0; j < 8; ++j) {
                int row_loc = j * 16 + srow;
                int kc = ss ^ ((row_loc >> 1) & 3);
                gload16(gb + (size_t)(roff + row_loc) * KD + k0 + kc * 8, lb + j * 512);
            }
        }
        __syncthreads();

        s16x8 fah[4], fal[4], fbh[4], fbl[4];
#pragma unroll
        for (int am = 0; am < 4; ++am) {
            int m_loc = wm * 64 + am * 16 + ln;
            int sl = (g ^ ((m_loc >> 1) & 3)) * 8;
            fah[am] = *(const s16x8*)&Ah[m_loc * 32 + sl];
            fal[am] = *(const s16x8*)&Al[m_loc * 32 + sl];
        }
#pragma unroll
        for (int bn = 0; bn < 4; ++bn) {
            int n_loc = wn * 64 + bn * 16 + ln;
            int sl = (g ^ ((n_loc >> 1) & 3)) * 8;
            fbh[bn] = *(const s16x8*)&Bh[n_loc * 32 + sl];
            fbl[bn] = *(const s16x8*)&Bl[n_loc * 32 + sl];
        }
#pragma unroll
        for (int am = 0; am < 4; ++am)
#pragma unroll
            for (int bn = 0; bn < 4; ++bn) {
                acc[am][bn] = MFMA16(fah[am], fbh[bn], acc[am][bn]);
                acc[am][bn] = MFMA16(fah[am], fbl[bn], acc[am][bn]);
                acc[am][bn] = MFMA16(fal[am], fbh[bn], acc[am][bn]);
            }
    }

#pragma unroll
    for (int am = 0; am < 4; ++am)
#pragma unroll
        for (int bn = 0; bn < 4; ++bn) {
            int n = n0 + wn * 64 + bn * 16 + ln;
            float bv = bias[n];
#pragma unroll
            for (int r = 0; r < 4; ++r) {
                int m = m0 + wm * 64 + am * 16 + g * 4 + r;
                out[(size_t)m * ND + n] = acc[am][bn][r] + bv;
            }
        }
}

// ---------------------------------------------------------------------------
extern "C" void kernel_launch(void* const* d_in, const int* in_sizes, int n_in,
                              void* d_out, int out_size, void* d_ws, size_t ws_size,
                              hipStream_t stream)
{
    const float* x     = (const float*)d_in[0];
    const float* W_kqv = (const float*)d_in[1];
    const float* b_kqv = (const float*)d_in[2];
    const float* W_out = (const float*)d_in[3];
    const float* b_out = (const float*)d_in[4];
    float* out = (float*)d_out;

    char* ws = (char*)d_ws;
    const size_t MB = 1024 * 1024;
    // ws [0,48MB): Q/K/V hi+lo bf16 (V transposed). After attn: [0,4MB) Wout^T.
    unsigned short* Qh = (unsigned short*)(ws);
    unsigned short* Ql = Qh + 4194304;
    unsigned short* Kh = Ql + 4194304;
    unsigned short* Kl = Kh + 4194304;
    unsigned short* Vh = Kl + 4194304;
    unsigned short* Vl = Vh + 4194304;
    // ws [48,60MB): Wkqv^T parts during GEMM1; then [48,64MB): Y parts.
    unsigned short* WhT = (unsigned short*)(ws + 48 * MB);
    unsigned short* WlT = WhT + 3145728;
    unsigned short* Yh  = (unsigned short*)(ws + 48 * MB);
    unsigned short* Yl  = Yh + 4194304;
    unsigned short* WoTh = (unsigned short*)(ws);
    unsigned short* WoTl = WoTh + 1048576;
    // X split lives in d_out (16 MB): dead until out_gemm rewrites all of it.
    unsigned short* Xh = (unsigned short*)d_out;
    unsigned short* Xl = Xh + 4194304;

    splitX_kernel<<<dim3(MTOT * EMBED / (256 * 8)), 256, 0, stream>>>(x, Xh, Xl);
    splitT_kernel<<<dim3(3 * EMBED / 32, EMBED / 32), 256, 0, stream>>>(
        W_kqv, WhT, WlT, EMBED, 3 * EMBED);
    qkv_gemm_kernel<<<dim3(3 * EMBED / 128, MTOT / 128), 256, 0, stream>>>(
        Xh, Xl, WhT, WlT, b_kqv, Qh, Ql, Kh, Kl, Vh, Vl);
    attn_kernel<<<dim3(BHTOT * (SEQ / 64)), 256, 0, stream>>>(
        Qh, Ql, Kh, Kl, Vh, Vl, Yh, Yl);
    splitT_kernel<<<dim3(EMBED / 32, EMBED / 32), 256, 0, stream>>>(
        W_out, WoTh, WoTl, EMBED, EMBED);
    out_gemm_kernel<<<dim3(EMBED / 128, MTOT / 128), 256, 0, stream>>>(
        Yh, Yl, WoTh, WoTl, b_out, out);
}

// Round 5
// 224.193 us; speedup vs baseline: 4.5040x; 1.1287x over previous
//
#include <hip/hip_runtime.h>
#include <math.h>

#define EMBED 1024
#define NH    16
#define DH    64
#define BATCH 2
#define SEQ   2048
#define MTOT  4096
#define BHTOT 32

typedef float f32x4  __attribute__((ext_vector_type(4)));
typedef float f32x16 __attribute__((ext_vector_type(16)));
typedef short s16x8  __attribute__((ext_vector_type(8)));
typedef short s16x4  __attribute__((ext_vector_type(4)));
typedef unsigned u32x2 __attribute__((ext_vector_type(2)));
typedef unsigned u32x4 __attribute__((ext_vector_type(4)));

#define AS1 __attribute__((address_space(1)))
#define AS3 __attribute__((address_space(3)))

__device__ __forceinline__ unsigned short bf16_rne(float f) {
    unsigned u = __builtin_bit_cast(unsigned, f);
    return (unsigned short)((u + 0x7FFFu + ((u >> 16) & 1u)) >> 16);
}
__device__ __forceinline__ float bf16_f(unsigned short h) {
    unsigned u = ((unsigned)h) << 16;
    return __builtin_bit_cast(float, u);
}
__device__ __forceinline__ void split2(float v, unsigned short& hi, unsigned short& lo) {
    hi = bf16_rne(v);
    lo = bf16_rne(v - bf16_f(hi));
}
__device__ __forceinline__ void gload16(const void* g, void* l) {
    __builtin_amdgcn_global_load_lds((const AS1 void*)g, (AS3 void*)l, 16, 0, 0);
}
__device__ __forceinline__ unsigned cvt_pk_bf16(float lo, float hi) {
    unsigned r;
    asm volatile("v_cvt_pk_bf16_f32 %0, %1, %2" : "=v"(r) : "v"(lo), "v"(hi));
    return r;
}
#define MFMA16(a, b, c) __builtin_amdgcn_mfma_f32_16x16x32_bf16((a), (b), (c), 0, 0, 0)
#define MFMA32(a, b, c) __builtin_amdgcn_mfma_f32_32x32x16_bf16((a), (b), (c), 0, 0, 0)

// ---------------------------------------------------------------------------
// splitX: X fp32 [M][K] -> Xh, Xl bf16 (same layout, hi/lo split)
// ---------------------------------------------------------------------------
__global__ __launch_bounds__(256)
void splitX_kernel(const float* __restrict__ X, unsigned short* __restrict__ Xh,
                   unsigned short* __restrict__ Xl)
{
    const size_t i = ((size_t)blockIdx.x * 256 + threadIdx.x) * 8;
    float4 a = *(const float4*)&X[i];
    float4 b = *(const float4*)&X[i + 4];
    float v[8] = {a.x, a.y, a.z, a.w, b.x, b.y, b.z, b.w};
    s16x8 h8, l8;
#pragma unroll
    for (int e = 0; e < 8; ++e) {
        unsigned short h, l; split2(v[e], h, l);
        h8[e] = (short)h; l8[e] = (short)l;
    }
    *(s16x8*)&Xh[i] = h8;
    *(s16x8*)&Xl[i] = l8;
}

// ---------------------------------------------------------------------------
// splitT: W fp32 [Kd][Nd]  ->  HiT, LoT bf16 [Nd][Kd] (transposed + hi/lo split)
// ---------------------------------------------------------------------------
__global__ __launch_bounds__(256)
void splitT_kernel(const float* __restrict__ W, unsigned short* __restrict__ HiT,
                   unsigned short* __restrict__ LoT, int Kd, int Nd)
{
    __shared__ float T[32][33];
    const int tid = threadIdx.x;
    const int n0 = blockIdx.x * 32, k0 = blockIdx.y * 32;
    {
        const int row = tid >> 3, c4 = (tid & 7) * 4;
        float4 v = *(const float4*)&W[(size_t)(k0 + row) * Nd + n0 + c4];
        T[row][c4] = v.x; T[row][c4 + 1] = v.y; T[row][c4 + 2] = v.z; T[row][c4 + 3] = v.w;
    }
    __syncthreads();
    {
        const int nr = tid >> 3, c4 = (tid & 7) * 4;
        s16x4 h4, l4;
#pragma unroll
        for (int e = 0; e < 4; ++e) {
            unsigned short h, l;
            split2(T[c4 + e][nr], h, l);
            h4[e] = (short)h; l4[e] = (short)l;
        }
        *(s16x4*)&HiT[(size_t)(n0 + nr) * Kd + k0 + c4] = h4;
        *(s16x4*)&LoT[(size_t)(n0 + nr) * Kd + k0 + c4] = l4;
    }
}

// ---------------------------------------------------------------------------
// QKV GEMM (all-bf16): Xsplit [4096][1024] @ Wkqv^T-split [3072][1024] + bias
//   -> Qh/Ql/Kh/Kl [bh][t][64], Vh/Vl transposed [bh][64][t]  (Q scaled 0.125)
// ---------------------------------------------------------------------------
__global__ __launch_bounds__(256)
void qkv_gemm_kernel(const unsigned short* __restrict__ Xh_g, const unsigned short* __restrict__ Xl_g,
                     const unsigned short* __restrict__ BhT, const unsigned short* __restrict__ BlT,
                     const float* __restrict__ bias,
                     unsigned short* __restrict__ Qh, unsigned short* __restrict__ Ql,
                     unsigned short* __restrict__ Kh, unsigned short* __restrict__ Kl,
                     unsigned short* __restrict__ Vh, unsigned short* __restrict__ Vl)
{
    constexpr int KD = 1024;
    __shared__ __align__(16) short Ah[128 * 32], Al[128 * 32];
    __shared__ __align__(16) short Bh[128 * 32], Bl[128 * 32];

    const int tid = threadIdx.x, lane = tid & 63, wid = tid >> 6;
    const int g = lane >> 4, ln = lane & 15;
    const int wm = wid >> 1, wn = wid & 1;
    const int m0 = blockIdx.y * 128, n0 = blockIdx.x * 128;

    f32x4 acc[4][4];
#pragma unroll
    for (int i = 0; i < 4; ++i)
#pragma unroll
        for (int j = 0; j < 4; ++j) acc[i][j] = (f32x4){0.f, 0.f, 0.f, 0.f};

    const int srow = lane >> 2, ss = lane & 3;

    for (int k0 = 0; k0 < KD; k0 += 32) {
        __syncthreads();
        {
            const unsigned short* gb;
            short* lb;
            int roff;
            if (wid == 0) { gb = Xh_g; lb = Ah; roff = m0; }
            else if (wid == 1) { gb = Xl_g; lb = Al; roff = m0; }
            else if (wid == 2) { gb = BhT; lb = Bh; roff = n0; }
            else { gb = BlT; lb = Bl; roff = n0; }
#pragma unroll
            for (int j = 0; j < 8; ++j) {
                int row_loc = j * 16 + srow;
                int kc = ss ^ ((row_loc >> 1) & 3);
                gload16(gb + (size_t)(roff + row_loc) * KD + k0 + kc * 8, lb + j * 512);
            }
        }
        __syncthreads();

        s16x8 fah[4], fal[4], fbh[4], fbl[4];
#pragma unroll
        for (int am = 0; am < 4; ++am) {
            int m_loc = wm * 64 + am * 16 + ln;
            int sl = (g ^ ((m_loc >> 1) & 3)) * 8;
            fah[am] = *(const s16x8*)&Ah[m_loc * 32 + sl];
            fal[am] = *(const s16x8*)&Al[m_loc * 32 + sl];
        }
#pragma unroll
        for (int bn = 0; bn < 4; ++bn) {
            int n_loc = wn * 64 + bn * 16 + ln;
            int sl = (g ^ ((n_loc >> 1) & 3)) * 8;
            fbh[bn] = *(const s16x8*)&Bh[n_loc * 32 + sl];
            fbl[bn] = *(const s16x8*)&Bl[n_loc * 32 + sl];
        }
#pragma unroll
        for (int am = 0; am < 4; ++am)
#pragma unroll
            for (int bn = 0; bn < 4; ++bn) {
                acc[am][bn] = MFMA16(fah[am], fbh[bn], acc[am][bn]);
                acc[am][bn] = MFMA16(fah[am], fbl[bn], acc[am][bn]);
                acc[am][bn] = MFMA16(fal[am], fbh[bn], acc[am][bn]);
            }
    }

#pragma unroll
    for (int am = 0; am < 4; ++am)
#pragma unroll
        for (int bn = 0; bn < 4; ++bn) {
            int n = n0 + wn * 64 + bn * 16 + ln;
            float bv = bias[n];
            int sec = n >> 10, cc = n & 1023, h = cc >> 6, d = cc & 63;
#pragma unroll
            for (int r = 0; r < 4; ++r) {
                int m = m0 + wm * 64 + am * 16 + g * 4 + r;
                int bb = m >> 11, t = m & 2047;
                int bh_i = bb * NH + h;
                float val = acc[am][bn][r] + bv;
                unsigned short hi, lo;
                if (sec == 0) {
                    val *= 0.125f; split2(val, hi, lo);
                    size_t idx = ((size_t)bh_i * SEQ + t) * DH + d;
                    Qh[idx] = hi; Ql[idx] = lo;
                } else if (sec == 1) {
                    split2(val, hi, lo);
                    size_t idx = ((size_t)bh_i * SEQ + t) * DH + d;
                    Kh[idx] = hi; Kl[idx] = lo;
                } else {
                    split2(val, hi, lo);
                    size_t idx = ((size_t)bh_i * DH + d) * SEQ + t;   // V transposed
                    Vh[idx] = hi; Vl[idx] = lo;
                }
            }
        }
}

// ---------------------------------------------------------------------------
// Attention, 32x32 swapped-operand structure.
// Block = 128 q-rows of one (b,h); 4 waves x 32 q-rows. Per kv-tile (64 keys):
//   S^T = mfma32(K, Q)  -> lane owns q = lane&31 (keys split lane<32 / >=32)
//   in-register softmax (1 shfl_xor(32) per reduce)
//   P -> bf16 via v_cvt_pk_bf16_f32 + permlane32_swap (no LDS)
//   Y^T = mfma32(V^T, P) -> cols = q, alpha rescale is lane-uniform
// K/V staged in LDS (hi/lo, XOR-swizzled) via global_load_lds. 2 barriers/iter.
// Epilogue: LDS transpose bounce -> coalesced Y (row-major) writes.
// ---------------------------------------------------------------------------
__global__ __launch_bounds__(256)
void attn_kernel(const unsigned short* __restrict__ Qh_g, const unsigned short* __restrict__ Ql_g,
                 const unsigned short* __restrict__ Kh_g, const unsigned short* __restrict__ Kl_g,
                 const unsigned short* __restrict__ Vh_g, const unsigned short* __restrict__ Vl_g,
                 unsigned short* __restrict__ Yh, unsigned short* __restrict__ Yl)
{
    __shared__ __align__(16) short SM[16384];   // 32 KB
    short* Ksh = SM;
    short* Ksl = SM + 4096;
    short* Vsh = SM + 8192;
    short* Vsl = SM + 12288;

    const int tid = threadIdx.x, lane = tid & 63, wid = tid >> 6;
    const int l31 = lane & 31, l5 = lane >> 5;
    const int bid = blockIdx.x;
    const int qb = 15 - (bid >> 5), bh = bid & 31;   // heavy q-tiles first
    const int Q0 = qb * 128;
    const int qg = Q0 + wid * 32 + l31;              // this lane's q row

    // Q fragments from global (once per block)
    s16x8 qfh[4], qfl[4];
    {
        const size_t qo = ((size_t)bh * SEQ + qg) * DH;
#pragma unroll
        for (int t = 0; t < 4; ++t) {
            const int ch = t * 2 + l5;
            qfh[t] = *(const s16x8*)&Qh_g[qo + ch * 8];
            qfl[t] = *(const s16x8*)&Ql_g[qo + ch * 8];
        }
    }

    float m_i = -INFINITY, l_i = 0.f;
    f32x16 yacc[2];
#pragma unroll
    for (int e = 0; e < 16; ++e) { yacc[0][e] = 0.f; yacc[1][e] = 0.f; }

    const int srow = lane >> 3, ss = lane & 7;
    const int KT = 2 * qb + 2;

    for (int kt = 0; kt < KT; ++kt) {
        __syncthreads();   // all waves done reading prior K/V tiles
        {
            const unsigned short* gb;
            short* lb;
            if (wid == 0) { gb = Kh_g; lb = Ksh; }
            else if (wid == 1) { gb = Kl_g; lb = Ksl; }
            else if (wid == 2) { gb = Vh_g; lb = Vsh; }
            else { gb = Vl_g; lb = Vsl; }
            const bool isK = (wid < 2);
#pragma unroll
            for (int j = 0; j < 8; ++j) {
                int row = j * 8 + srow;
                int kc = ss ^ (row & 7);
                const unsigned short* src = isK
                    ? gb + ((size_t)bh * SEQ + kt * 64 + row) * DH + kc * 8
                    : gb + ((size_t)bh * DH + row) * SEQ + kt * 64 + kc * 8;
                gload16(src, lb + j * 512);
            }
        }
        __syncthreads();   // tiles ready

        if (kt * 64 > Q0 + wid * 32 + 31) continue;   // fully masked for this wave

        // ---- S^T = K . Q  (3-combo split; rows=keys, cols=q)
        f32x16 s[2];
#pragma unroll
        for (int e = 0; e < 16; ++e) { s[0][e] = 0.f; s[1][e] = 0.f; }
#pragma unroll
        for (int t = 0; t < 4; ++t) {
#pragma unroll
            for (int kb = 0; kb < 2; ++kb) {
                const int row = kb * 32 + l31;
                const int sl = ((t * 2 + l5) ^ (row & 7)) * 8;
                s16x8 kh = *(const s16x8*)&Ksh[row * 64 + sl];
                s16x8 kl = *(const s16x8*)&Ksl[row * 64 + sl];
                s[kb] = MFMA32(kh, qfh[t], s[kb]);
                s[kb] = MFMA32(kl, qfh[t], s[kb]);
                s[kb] = MFMA32(kh, qfl[t], s[kb]);
            }
        }

        // ---- causal mask (only near the diagonal)
        if (kt * 64 + 63 > Q0 + wid * 32) {
#pragma unroll
            for (int kb = 0; kb < 2; ++kb)
#pragma unroll
                for (int r = 0; r < 16; ++r) {
                    const int key = kt * 64 + kb * 32 + (r & 3) + 8 * (r >> 2) + 4 * l5;
                    if (key > qg) s[kb][r] = -INFINITY;
                }
        }

        // ---- online softmax, fully in-register (q = lane&31)
        float mx = s[0][0];
#pragma unroll
        for (int r = 1; r < 16; ++r) mx = fmaxf(mx, s[0][r]);
#pragma unroll
        for (int r = 0; r < 16; ++r) mx = fmaxf(mx, s[1][r]);
        mx = fmaxf(mx, __shfl_xor(mx, 32));
        const float mn = fmaxf(m_i, mx);
        const float al = __expf(m_i - mn);
        float ls = 0.f;
#pragma unroll
        for (int kb = 0; kb < 2; ++kb)
#pragma unroll
            for (int r = 0; r < 16; ++r) {
                s[kb][r] = __expf(s[kb][r] - mn);
                ls += s[kb][r];
            }
        ls += __shfl_xor(ls, 32);
        l_i = l_i * al + ls;
        m_i = mn;
#pragma unroll
        for (int e = 0; e < 16; ++e) { yacc[0][e] *= al; yacc[1][e] *= al; }

        // ---- P (bf16) fragments in-register: cvt_pk + permlane32_swap
        unsigned pk[2][8];
#pragma unroll
        for (int kb = 0; kb < 2; ++kb)
#pragma unroll
            for (int j = 0; j < 8; ++j)
                pk[kb][j] = cvt_pk_bf16(s[kb][2 * j], s[kb][2 * j + 1]);
        s16x8 pf[2][2];
#pragma unroll
        for (int kb = 0; kb < 2; ++kb) {
            u32x2 sA = __builtin_amdgcn_permlane32_swap(pk[kb][0], pk[kb][2], false, false);
            u32x2 sB = __builtin_amdgcn_permlane32_swap(pk[kb][1], pk[kb][3], false, false);
            u32x4 w0 = {sA[0], sB[0], sA[1], sB[1]};
            pf[kb][0] = __builtin_bit_cast(s16x8, w0);
            u32x2 sC = __builtin_amdgcn_permlane32_swap(pk[kb][4], pk[kb][6], false, false);
            u32x2 sD = __builtin_amdgcn_permlane32_swap(pk[kb][5], pk[kb][7], false, false);
            u32x4 w1 = {sC[0], sD[0], sC[1], sD[1]};
            pf[kb][1] = __builtin_bit_cast(s16x8, w1);
        }

        // ---- Y^T += V^T . P  (2-combo: ph*vh + ph*vl; rows=d, cols=q)
#pragma unroll
        for (int dt = 0; dt < 2; ++dt) {
#pragma unroll
            for (int t = 0; t < 4; ++t) {
                const int row = dt * 32 + l31;
                const int sl = ((t * 2 + l5) ^ (row & 7)) * 8;
                s16x8 vh = *(const s16x8*)&Vsh[row * 64 + sl];
                s16x8 vl = *(const s16x8*)&Vsl[row * 64 + sl];
                const s16x8 pfr = pf[t >> 1][t & 1];
                yacc[dt] = MFMA32(vh, pfr, yacc[dt]);
                yacc[dt] = MFMA32(vl, pfr, yacc[dt]);
            }
        }
    }

    // ---- epilogue: normalize, split, LDS transpose bounce, coalesced write
    __syncthreads();   // everyone done with K/V LDS
    const float inv = 1.f / l_i;
    const int qlcl = wid * 32 + l31;
#pragma unroll
    for (int dt = 0; dt < 2; ++dt)
#pragma unroll
        for (int rq = 0; rq < 4; ++rq) {
            const int d0 = dt * 32 + rq * 8 + 4 * l5;
            s16x4 h4, l4;
#pragma unroll
            for (int c = 0; c < 4; ++c) {
                unsigned short hh, ll;
                split2(yacc[dt][rq * 4 + c] * inv, hh, ll);
                h4[c] = (short)hh; l4[c] = (short)ll;
            }
            const int base = qlcl * 64 + (((d0 >> 3) ^ (qlcl & 7)) * 8) + (d0 & 7);
            *(s16x4*)&SM[base] = h4;
            *(s16x4*)&SM[8192 + base] = l4;
        }
    __syncthreads();
    const int b = bh >> 4, h = bh & 15;
#pragma unroll
    for (int i = 0; i < 4; ++i) {
        const int idx = tid + i * 256;
        const int row = idx >> 3, ch = idx & 7;
        const int sl = (ch ^ (row & 7)) * 8;
        s16x8 vh8 = *(const s16x8*)&SM[row * 64 + sl];
        s16x8 vl8 = *(const s16x8*)&SM[8192 + row * 64 + sl];
        const size_t o = ((size_t)(b * SEQ + Q0 + row)) * EMBED + h * DH + ch * 8;
        *(s16x8*)&Yh[o] = vh8;
        *(s16x8*)&Yl[o] = vl8;
    }
}

// ---------------------------------------------------------------------------
// Out GEMM: Y-split bf16 [4096][1024] @ Wout^T-split bf16 [1024][1024] + bias
// ---------------------------------------------------------------------------
__global__ __launch_bounds__(256)
void out_gemm_kernel(const unsigned short* __restrict__ Yh_g, const unsigned short* __restrict__ Yl_g,
                     const unsigned short* __restrict__ WhT, const unsigned short* __restrict__ WlT,
                     const float* __restrict__ bias, float* __restrict__ out)
{
    constexpr int KD = 1024, ND = 1024;
    __shared__ __align__(16) short Ah[128 * 32], Al[128 * 32];
    __shared__ __align__(16) short Bh[128 * 32], Bl[128 * 32];

    const int tid = threadIdx.x, lane = tid & 63, wid = tid >> 6;
    const int g = lane >> 4, ln = lane & 15;
    const int wm = wid >> 1, wn = wid & 1;
    const int m0 = blockIdx.y * 128, n0 = blockIdx.x * 128;

    f32x4 acc[4][4];
#pragma unroll
    for (int i = 0; i < 4; ++i)
#pragma unroll
        for (int j = 0; j < 4; ++j) acc[i][j] = (f32x4){0.f, 0.f, 0.f, 0.f};

    const int srow = lane >> 2, ss = lane & 3;

    for (int k0 = 0; k0 < KD; k0 += 32) {
        __syncthreads();
        {
            const unsigned short* gb;
            short* lb;
            int roff;
            if (wid == 0) { gb = Yh_g; lb = Ah; roff = m0; }
            else if (wid == 1) { gb = Yl_g; lb = Al; roff = m0; }
            else if (wid == 2) { gb = WhT; lb = Bh; roff = n0; }
            else { gb = WlT; lb = Bl; roff = n0; }
#pragma unroll
            for (int j = 0; j < 8; ++j) {
                int row_loc = j * 16 + srow;
                int kc = ss ^ ((row_loc >> 1) & 3);
                gload16(gb + (size_t)(roff + row_loc) * KD + k0 + kc * 8, lb + j * 512);
            }
        }
        __syncthreads();

        s16x8 fah[4], fal[4], fbh[4], fbl[4];
#pragma unroll
        for (int am = 0; am < 4; ++am) {
            int m_loc = wm * 64 + am * 16 + ln;
            int sl = (g ^ ((m_loc >> 1) & 3)) * 8;
            fah[am] = *(const s16x8*)&Ah[m_loc * 32 + sl];
            fal[am] = *(const s16x8*)&Al[m_loc * 32 + sl];
        }
#pragma unroll
        for (int bn = 0; bn < 4; ++bn) {
            int n_loc = wn * 64 + bn * 16 + ln;
            int sl = (g ^ ((n_loc >> 1) & 3)) * 8;
            fbh[bn] = *(const s16x8*)&Bh[n_loc * 32 + sl];
            fbl[bn] = *(const s16x8*)&Bl[n_loc * 32 + sl];
        }
#pragma unroll
        for (int am = 0; am < 4; ++am)
#pragma unroll
            for (int bn = 0; bn < 4; ++bn) {
                acc[am][bn] = MFMA16(fah[am], fbh[bn], acc[am][bn]);
                acc[am][bn] = MFMA16(fah[am], fbl[bn], acc[am][bn]);
                acc[am][bn] = MFMA16(fal[am], fbh[bn], acc[am][bn]);
            }
    }

#pragma unroll
    for (int am = 0; am < 4; ++am)
#pragma unroll
        for (int bn = 0; bn < 4; ++bn) {
            int n = n0 + wn * 64 + bn * 16 + ln;
            float bv = bias[n];
#pragma unroll
            for (int r = 0; r < 4; ++r) {
                int m = m0 + wm * 64 + am * 16 + g * 4 + r;
                out[(size_t)m * ND + n] = acc[am][bn][r] + bv;
            }
        }
}

// ---------------------------------------------------------------------------
extern "C" void kernel_launch(void* const* d_in, const int* in_sizes, int n_in,
                              void* d_out, int out_size, void* d_ws, size_t ws_size,
                              hipStream_t stream)
{
    const float* x     = (const float*)d_in[0];
    const float* W_kqv = (const float*)d_in[1];
    const float* b_kqv = (const float*)d_in[2];
    const float* W_out = (const float*)d_in[3];
    const float* b_out = (const float*)d_in[4];
    float* out = (float*)d_out;

    char* ws = (char*)d_ws;
    const size_t MB = 1024 * 1024;
    unsigned short* Qh = (unsigned short*)(ws);
    unsigned short* Ql = Qh + 4194304;
    unsigned short* Kh = Ql + 4194304;
    unsigned short* Kl = Kh + 4194304;
    unsigned short* Vh = Kl + 4194304;
    unsigned short* Vl = Vh + 4194304;
    unsigned short* WhT = (unsigned short*)(ws + 48 * MB);
    unsigned short* WlT = WhT + 3145728;
    unsigned short* Yh  = (unsigned short*)(ws + 48 * MB);
    unsigned short* Yl  = Yh + 4194304;
    unsigned short* WoTh = (unsigned short*)(ws);
    unsigned short* WoTl = WoTh + 1048576;
    // X split lives in d_out (16 MB): dead until out_gemm rewrites all of it.
    unsigned short* Xh = (unsigned short*)d_out;
    unsigned short* Xl = Xh + 4194304;

    splitX_kernel<<<dim3(MTOT * EMBED / (256 * 8)), 256, 0, stream>>>(x, Xh, Xl);
    splitT_kernel<<<dim3(3 * EMBED / 32, EMBED / 32), 256, 0, stream>>>(
        W_kqv, WhT, WlT, EMBED, 3 * EMBED);
    qkv_gemm_kernel<<<dim3(3 * EMBED / 128, MTOT / 128), 256, 0, stream>>>(
        Xh, Xl, WhT, WlT, b_kqv, Qh, Ql, Kh, Kl, Vh, Vl);
    attn_kernel<<<dim3(BHTOT * (SEQ / 128)), 256, 0, stream>>>(
        Qh, Ql, Kh, Kl, Vh, Vl, Yh, Yl);
    splitT_kernel<<<dim3(EMBED / 32, EMBED / 32), 256, 0, stream>>>(
        W_out, WoTh, WoTl, EMBED, EMBED);
    out_gemm_kernel<<<dim3(EMBED / 128, MTOT / 128), 256, 0, stream>>>(
        Yh, Yl, WoTh, WoTl, b_out, out);
}